// Round 1
// baseline (465.136 us; speedup 1.0000x reference)
//
#include <hip/hip_runtime.h>

#define B_  64
#define T_  256
#define F_  16
#define H_  128
#define G4H 512   // 4*H

__device__ __forceinline__ float sigm(float x)  { return 1.0f / (1.0f + __expf(-x)); }
__device__ __forceinline__ float tanh_(float x) { return 2.0f / (1.0f + __expf(-2.0f * x)) - 1.0f; }

// Kernel 1: W_hh [F,4H,H] -> W_T viewed as float4 array: wt4[(f*32 + k4)*512 + g] = W_hh[f, g, 4k4 .. 4k4+3]
// Each block: one (f, 64-row g-chunk). Coalesced read along k, coalesced write along (g,c).
__global__ void transpose_whh(const float* __restrict__ whh, float* __restrict__ wt) {
    __shared__ float ls[64][129];
    int f = blockIdx.x >> 3, gblk = blockIdx.x & 7;
    int t = threadIdx.x;  // 0..255
    const float* src = whh + ((size_t)f * G4H + gblk * 64) * H_;
#pragma unroll
    for (int i = 0; i < 32; ++i) {
        int idx = i * 256 + t;          // idx = g'*128 + k
        ls[idx >> 7][idx & 127] = src[idx];
    }
    __syncthreads();
    float* dst = wt + (size_t)f * 65536 + gblk * 256;
#pragma unroll
    for (int k4 = 0; k4 < 32; ++k4) {
        // dst element ((f*32+k4)*512 + gblk*64 + g'')*4 + c, with t = g''*4 + c
        dst[k4 * 2048 + t] = ls[t >> 2][k4 * 4 + (t & 3)];
    }
}

// Kernel 2: one block per (f, b). 512 threads; thread g owns gate-row g (128 weights in VGPRs).
__global__ __launch_bounds__(512, 2) void lstm_main(
    const float* __restrict__ x, const int* __restrict__ index,
    const float* __restrict__ wih_g, const float* __restrict__ bias_g,
    const float* __restrict__ wt, float* __restrict__ hout)
{
    __shared__ float xsh[T_];
    __shared__ float hsh[H_];
    __shared__ float gsh[G4H];

    const int f = blockIdx.x, b = blockIdx.y;
    const int g = threadIdx.x;

    const float wih = wih_g[f * G4H + g];
    const float bb  = bias_g[f * G4H + g];

    float4 w4[32];
    const float4* wt4 = (const float4*)wt + (size_t)f * 32 * 512 + g;
#pragma unroll
    for (int k4 = 0; k4 < 32; ++k4) w4[k4] = wt4[k4 * 512];

    if (g < T_) xsh[g] = x[(b * T_ + g) * F_ + f];
    if (g < H_) hsh[g] = 0.0f;
    float c = 0.0f;

    const int start = index[2 * b], end = index[2 * b + 1];

    for (int t = start; t < end; ++t) {
        __syncthreads();                      // hsh (and xsh on first iter) visible
        float a0 = fmaf(xsh[t], wih, bb), a1 = 0.0f, a2 = 0.0f, a3 = 0.0f;
        const float4* h4 = (const float4*)hsh;
#pragma unroll
        for (int k4 = 0; k4 < 32; ++k4) {
            float4 hv = h4[k4];
            float4 ww = w4[k4];
            a0 = fmaf(hv.x, ww.x, a0);
            a1 = fmaf(hv.y, ww.y, a1);
            a2 = fmaf(hv.z, ww.z, a2);
            a3 = fmaf(hv.w, ww.w, a3);
        }
        float acc = (a0 + a1) + (a2 + a3);
        int type = g >> 7;                    // wave-uniform (64-lane waves)
        float v = (type == 2) ? tanh_(acc) : sigm(acc);
        gsh[g] = v;
        __syncthreads();                      // gates visible; all hsh reads done
        if (g < H_) {
            float gi = gsh[g], gf = gsh[g + 128], gg = gsh[g + 256], go = gsh[g + 384];
            c = fmaf(gf, c, gi * gg);
            hsh[g] = go * tanh_(c);
        }
    }
    __syncthreads();
    if (g < H_) hout[((size_t)b * F_ + f) * H_ + g] = hsh[g];
}

// Kernel 3: per-batch epilogue: mean over H -> conv3 (pad 1) -> sigmoid gate -> gated fc to 2 outputs.
__global__ void epilogue(const float* __restrict__ hout, const float* __restrict__ conv_w,
                         const float* __restrict__ fc_w, const float* __restrict__ fc_b,
                         float* __restrict__ out)
{
    const int b = blockIdx.x, t = threadIdx.x;   // 128 threads
    const int lane = t & 63, wv = t >> 6;
    __shared__ float part[2][16];
    __shared__ float gate_sh[16];

    float hv[16];
#pragma unroll
    for (int f = 0; f < 16; ++f) hv[f] = hout[((size_t)b * 16 + f) * 128 + t];

#pragma unroll
    for (int f = 0; f < 16; ++f) {
        float s = hv[f];
#pragma unroll
        for (int off = 32; off >= 1; off >>= 1) s += __shfl_down(s, off, 64);
        if (lane == 0) part[wv][f] = s;
    }
    __syncthreads();
    if (t < 16) gate_sh[t] = (part[0][t] + part[1][t]) * (1.0f / 128.0f);  // means
    __syncthreads();
    float gate = 0.0f;
    if (t < 16) {
        float l  = (t > 0)  ? gate_sh[t - 1] : 0.0f;
        float mi = gate_sh[t];
        float r  = (t < 15) ? gate_sh[t + 1] : 0.0f;
        gate = sigm(l * conv_w[0] + mi * conv_w[1] + r * conv_w[2]);
    }
    __syncthreads();
    if (t < 16) gate_sh[t] = gate;
    __syncthreads();

    float acc0 = 0.0f, acc1 = 0.0f;
    const float2* fw2 = (const float2*)fc_w;
#pragma unroll
    for (int f = 0; f < 16; ++f) {
        float hg = hv[f] * gate_sh[f];
        float2 w2 = fw2[f * 128 + t];
        acc0 = fmaf(hg, w2.x, acc0);
        acc1 = fmaf(hg, w2.y, acc1);
    }
#pragma unroll
    for (int off = 32; off >= 1; off >>= 1) {
        acc0 += __shfl_down(acc0, off, 64);
        acc1 += __shfl_down(acc1, off, 64);
    }
    if (lane == 0) { part[wv][0] = acc0; part[wv][1] = acc1; }
    __syncthreads();
    if (t == 0) {
        out[b * 2 + 0] = part[0][0] + part[1][0] + fc_b[0];
        out[b * 2 + 1] = part[0][1] + part[1][1] + fc_b[1];
    }
}

extern "C" void kernel_launch(void* const* d_in, const int* in_sizes, int n_in,
                              void* d_out, int out_size, void* d_ws, size_t ws_size,
                              hipStream_t stream) {
    const float* x      = (const float*)d_in[0];
    const int*   index  = (const int*)  d_in[1];
    const float* W_ih   = (const float*)d_in[2];
    const float* W_hh   = (const float*)d_in[3];
    const float* bias   = (const float*)d_in[4];
    const float* conv_w = (const float*)d_in[5];
    const float* fc_w   = (const float*)d_in[6];
    const float* fc_b   = (const float*)d_in[7];
    float* out = (float*)d_out;

    float* wt   = (float*)d_ws;            // 16*512*128 = 1,048,576 floats (4 MB)
    float* hout = wt + 1048576;            // 64*16*128 = 131,072 floats (512 KB)

    transpose_whh<<<128, 256, 0, stream>>>(W_hh, wt);
    lstm_main<<<dim3(F_, B_), 512, 0, stream>>>(x, index, W_ih, bias, wt, hout);
    epilogue<<<B_, 128, 0, stream>>>(hout, conv_w, fc_w, fc_b, out);
}

// Round 2
// 323.240 us; speedup vs baseline: 1.4390x; 1.4390x over previous
//
#include <hip/hip_runtime.h>

typedef _Float16 half2_t __attribute__((ext_vector_type(2)));
typedef unsigned int uint_t;

#define B_  64
#define T_  256
#define F_  16
#define H_  128

__device__ __forceinline__ float rcp_(float x)  { return __builtin_amdgcn_rcpf(x); }
__device__ __forceinline__ float sigm(float x)  { return rcp_(1.0f + __expf(-x)); }
__device__ __forceinline__ float tanh_(float x) { return 2.0f * rcp_(1.0f + __expf(-2.0f * x)) - 1.0f; }

#if __has_builtin(__builtin_amdgcn_fdot2)
__device__ __forceinline__ float dot2(uint_t w, uint_t h, float a) {
    return __builtin_amdgcn_fdot2(__builtin_bit_cast(half2_t, w),
                                  __builtin_bit_cast(half2_t, h), a, false);
}
#else
__device__ __forceinline__ float dot2(uint_t w, uint_t h, float a) {
    half2_t W = __builtin_bit_cast(half2_t, w), H = __builtin_bit_cast(half2_t, h);
    return a + (float)W[0] * (float)H[0] + (float)W[1] * (float)H[1];
}
#endif

// Kernel 1: repack W_hh [F,4H,H] fp32 -> f16-pair layout keyed to the main kernel's
// per-thread register file. Thread tid=(i,ks) of block f owns rows {i+128m} x k-slice
// [32ks,32ks+32). Packed as uint4 wt[(f*16+q)*512+tid], component e: dword dd=q*4+e,
// m=dd>>4, kk=dd&15 -> f16 pair W[f, i+128m, 32ks+2kk .. +1].
__global__ void repack_w(const float* __restrict__ whh, uint_t* __restrict__ wt) {
    const int f = blockIdx.x, tid = threadIdx.x;
    const int i = tid >> 2, ks = tid & 3;
    const float* base = whh + (size_t)f * 512 * 128;
#pragma unroll
    for (int q = 0; q < 16; ++q) {
        uint_t tmp[4];
#pragma unroll
        for (int e = 0; e < 4; ++e) {
            int dd = q * 4 + e, m = dd >> 4, kk = dd & 15;
            int row = i + 128 * m, k0 = 32 * ks + 2 * kk;
            half2_t h = { (_Float16)base[row * 128 + k0], (_Float16)base[row * 128 + k0 + 1] };
            tmp[e] = __builtin_bit_cast(uint_t, h);
        }
        uint4 out = { tmp[0], tmp[1], tmp[2], tmp[3] };
        ((uint4*)wt)[((size_t)f * 16 + q) * 512 + tid] = out;
    }
}

// Kernel 2: one block per (f,b), 512 threads. Thread (i,ks): 4 gate rows x 32-k slice,
// weights in 16 uint4 VGPRs (f16 pairs), h in double-buffered LDS (f16), v_dot2 inner
// product, shfl_xor k-reduction, 1 barrier/step.
__global__ __launch_bounds__(512, 4) void lstm_main(
    const float* __restrict__ x, const int* __restrict__ index,
    const float* __restrict__ wih_g, const float* __restrict__ bias_g,
    const uint_t* __restrict__ wt, float* __restrict__ hout)
{
    __shared__ float xsh[T_];
    __shared__ alignas(16) unsigned short hsh[2][H_];

    const int f = blockIdx.x, b = blockIdx.y;
    const int tid = threadIdx.x;
    const int i = tid >> 2, ks = tid & 3;

    // weight preload: 16 coalesced uint4 loads, then force register residency
    uint4 w[16];
    const uint4* src = (const uint4*)wt + (size_t)f * 16 * 512 + tid;
#pragma unroll
    for (int q = 0; q < 16; ++q) w[q] = src[q * 512];
#pragma unroll
    for (int q = 0; q < 16; ++q)
        asm volatile("" : "+v"(w[q].x), "+v"(w[q].y), "+v"(w[q].z), "+v"(w[q].w));

    float wih4[4], b4[4];
#pragma unroll
    for (int m = 0; m < 4; ++m) {
        wih4[m] = wih_g[f * 512 + 128 * m + i];
        b4[m]   = bias_g[f * 512 + 128 * m + i];
    }

    if (tid < T_) xsh[tid] = x[((size_t)b * T_ + tid) * F_ + f];
    if (tid < H_) hsh[0][tid] = 0;

    const int start = index[2 * b], end = index[2 * b + 1];
    float c = 0.0f, hval = 0.0f;
    int p = 0;

    for (int t = start; t < end; ++t) {
        __syncthreads();                       // hsh[p] (and xsh on first iter) visible
        const uint4* h4 = (const uint4*)(&hsh[p][ks * 32]);
        float acc[4] = {0.f, 0.f, 0.f, 0.f};
#pragma unroll
        for (int q = 0; q < 4; ++q) {
            uint4 hq = h4[q];
#pragma unroll
            for (int m = 0; m < 4; ++m) {
                uint4 wq = w[m * 4 + q];
                acc[m] = dot2(wq.x, hq.x, acc[m]);
                acc[m] = dot2(wq.y, hq.y, acc[m]);
                acc[m] = dot2(wq.z, hq.z, acc[m]);
                acc[m] = dot2(wq.w, hq.w, acc[m]);
            }
        }
        // combine the 4 k-slices (lanes 4i'+ks, in-wave)
#pragma unroll
        for (int m = 0; m < 4; ++m) {
            acc[m] += __shfl_xor(acc[m], 1, 64);
            acc[m] += __shfl_xor(acc[m], 2, 64);
        }
        float xt = xsh[t];
        float pi = fmaf(xt, wih4[0], acc[0] + b4[0]);
        float pf = fmaf(xt, wih4[1], acc[1] + b4[1]);
        float pg = fmaf(xt, wih4[2], acc[2] + b4[2]);
        float po = fmaf(xt, wih4[3], acc[3] + b4[3]);
        float gi = sigm(pi), gf = sigm(pf), gg = tanh_(pg), go = sigm(po);
        c = fmaf(gf, c, gi * gg);
        hval = go * tanh_(c);
        if (ks == 0) {
            _Float16 hf = (_Float16)hval;
            hsh[p ^ 1][i] = __builtin_bit_cast(unsigned short, hf);
        }
        p ^= 1;
    }
    if (ks == 0) hout[((size_t)b * F_ + f) * H_ + i] = hval;
}

// Kernel 3: per-batch epilogue: mean over H -> conv3 (pad 1) -> sigmoid gate -> gated fc.
__global__ void epilogue(const float* __restrict__ hout, const float* __restrict__ conv_w,
                         const float* __restrict__ fc_w, const float* __restrict__ fc_b,
                         float* __restrict__ out)
{
    const int b = blockIdx.x, t = threadIdx.x;   // 128 threads
    const int lane = t & 63, wv = t >> 6;
    __shared__ float part[2][16];
    __shared__ float gate_sh[16];

    float hv[16];
#pragma unroll
    for (int f = 0; f < 16; ++f) hv[f] = hout[((size_t)b * 16 + f) * 128 + t];

#pragma unroll
    for (int f = 0; f < 16; ++f) {
        float s = hv[f];
#pragma unroll
        for (int off = 32; off >= 1; off >>= 1) s += __shfl_down(s, off, 64);
        if (lane == 0) part[wv][f] = s;
    }
    __syncthreads();
    if (t < 16) gate_sh[t] = (part[0][t] + part[1][t]) * (1.0f / 128.0f);  // means
    __syncthreads();
    float gate = 0.0f;
    if (t < 16) {
        float l  = (t > 0)  ? gate_sh[t - 1] : 0.0f;
        float mi = gate_sh[t];
        float r  = (t < 15) ? gate_sh[t + 1] : 0.0f;
        gate = sigm(fmaf(l, conv_w[0], fmaf(mi, conv_w[1], r * conv_w[2])));
    }
    __syncthreads();
    if (t < 16) gate_sh[t] = gate;
    __syncthreads();

    float acc0 = 0.0f, acc1 = 0.0f;
    const float2* fw2 = (const float2*)fc_w;
#pragma unroll
    for (int f = 0; f < 16; ++f) {
        float hg = hv[f] * gate_sh[f];
        float2 w2 = fw2[f * 128 + t];
        acc0 = fmaf(hg, w2.x, acc0);
        acc1 = fmaf(hg, w2.y, acc1);
    }
#pragma unroll
    for (int off = 32; off >= 1; off >>= 1) {
        acc0 += __shfl_down(acc0, off, 64);
        acc1 += __shfl_down(acc1, off, 64);
    }
    if (lane == 0) { part[wv][0] = acc0; part[wv][1] = acc1; }
    __syncthreads();
    if (t == 0) {
        out[b * 2 + 0] = part[0][0] + part[1][0] + fc_b[0];
        out[b * 2 + 1] = part[0][1] + part[1][1] + fc_b[1];
    }
}

extern "C" void kernel_launch(void* const* d_in, const int* in_sizes, int n_in,
                              void* d_out, int out_size, void* d_ws, size_t ws_size,
                              hipStream_t stream) {
    const float* x      = (const float*)d_in[0];
    const int*   index  = (const int*)  d_in[1];
    const float* W_ih   = (const float*)d_in[2];
    const float* W_hh   = (const float*)d_in[3];
    const float* bias   = (const float*)d_in[4];
    const float* conv_w = (const float*)d_in[5];
    const float* fc_w   = (const float*)d_in[6];
    const float* fc_b   = (const float*)d_in[7];
    float* out = (float*)d_out;

    uint_t* wt   = (uint_t*)d_ws;                          // 16*16*512 uint4 = 2 MB
    float*  hout = (float*)((char*)d_ws + 2 * 1024 * 1024); // 64*16*128 fp32 = 512 KB

    repack_w<<<F_, 512, 0, stream>>>(W_hh, wt);
    lstm_main<<<dim3(F_, B_), 512, 0, stream>>>(x, index, W_ih, bias, wt, hout);
    epilogue<<<B_, 128, 0, stream>>>(hout, conv_w, fc_w, fc_b, out);
}